// Round 5
// baseline (192.942 us; speedup 1.0000x reference)
//
#include <hip/hip_runtime.h>

#define N_NODES 50000
#define N_EDGES 800000
#define D_IN    256
#define D_OUT   128
#define EPS     1e-9f
#define BPAD    136     // Bs k-stride in ushorts: 272B rows (16B-aligned), 2-way bank alias = free

#define SCATTER_BLOCKS 196   // 196 * 4096 = 802816 >= 800000 edges
#define GEMM_MBLKS     391   // ceil(50000/128)

// bucket scatter: rows grouped 64/bucket; global atomics only per (block,bucket)
#define RPB    64
#define NBUCK  782           // ceil(50000/64)
#define BCAP   1344          // mean 1024 + 10 sigma; overflow ~impossible
#define GSTR   16            // gcnt stride in ints: one bucket per 64B line (kills same-line atomic storm)

typedef __attribute__((ext_vector_type(8))) short bf16x8;   // MFMA A/B frag (4 VGPRs)
typedef __attribute__((ext_vector_type(4))) float floatx4;  // MFMA C/D frag

__device__ __forceinline__ ushort f2bf(float x) {           // RTNE fp32 -> bf16
    unsigned u = __float_as_uint(x);
    u += 0x7fffu + ((u >> 16) & 1u);
    return (ushort)(u >> 16);
}

__device__ __forceinline__ bf16x8 packbf(float4 a, float4 b) {
    union { ushort us[8]; bf16x8 v; } r;
    r.us[0] = f2bf(a.x); r.us[1] = f2bf(a.y);
    r.us[2] = f2bf(a.z); r.us[3] = f2bf(a.w);
    r.us[4] = f2bf(b.x); r.us[5] = f2bf(b.y);
    r.us[6] = f2bf(b.z); r.us[7] = f2bf(b.w);
    return r.v;
}

// ---------------------------------------------------------------------------
// prep_small: (a) gcnt[NBUCK*GSTR] = 0  (b) Wb[n][k] = bf16 transposed [W0|W1].
// ---------------------------------------------------------------------------
#define WB_BLOCKS  32
__global__ __launch_bounds__(256) void prep_small(
    const float* __restrict__ W0, const float* __restrict__ W1,
    ushort* __restrict__ Wb, int* __restrict__ gcnt)
{
    int bid = blockIdx.x;
    int t   = threadIdx.x;
    if (bid == 0) {
        for (int i = t; i < NBUCK * GSTR; i += 256) gcnt[i] = 0;
    } else {
        int g  = (bid - 1) * 256 + t;
        int n  = g >> 5;                      // 0..255
        int kq = g & 31;                      // 8-elem k group
        const float* W = (n < 128) ? W0 : W1;
        int nn = n & 127;
        union { ushort us[8]; uint4 v; } tmp;
#pragma unroll
        for (int j = 0; j < 8; ++j)
            tmp.us[j] = f2bf(W[(size_t)(kq * 8 + j) * D_OUT + nn]);
        *(uint4*)&Wb[(size_t)n * D_IN + kq * 8] = tmp.v;
    }
}

// ---------------------------------------------------------------------------
// Fused kernel, BLOCK-role split, 512 threads.
//   bid < SCATTER_BLOCKS: LDS-aggregated bucket scatter of 4096 edges
//     (8/thread). LDS int atomics for ranks; one global atomicAdd per touched
//     (block,bucket) reserves a contiguous bedge range. gcnt padded to one
//     bucket per 64B line: per-line atomic serialization 3.1K -> 196 ops.
//   else: 128(M) x 128(N) gemm tile, 8 waves, each wave owns 16 rows.
//     A: global->register direct; B: LDS, two K=128 phases.
//     half 0: cols 0..127  -> bias0+relu+LN -> out[:, 0:128]
//     half 1: cols 128..255 -> raw bf16 -> Y1[M,128]
// ---------------------------------------------------------------------------
__global__ __launch_bounds__(512, 4) void gemm_scatter(
    const float* __restrict__ feat, const ushort* __restrict__ Wb,
    const float* __restrict__ bias, const float* __restrict__ scale,
    const float* __restrict__ offset,
    float* __restrict__ out, ushort* __restrict__ Y1,
    const int* __restrict__ er, const int* __restrict__ ec,
    const float* __restrict__ ev, int* __restrict__ gcnt,
    uint2* __restrict__ bedge)
{
    __shared__ __align__(16) ushort Bs[128 * BPAD];   // 34816 B

    const int t = threadIdx.x;

    if (blockIdx.x < SCATTER_BLOCKS) {
        int* hist = (int*)Bs;          // NBUCK ints
        int* base = hist + NBUCK;      // NBUCK ints (6.3KB total, fits)
        for (int i = t; i < NBUCK; i += 512) hist[i] = 0;
        __syncthreads();

        int ebase = blockIdx.x * 4096;
        int   bkt[8], rnk[8];
        uint2 pk[8];
#pragma unroll
        for (int u = 0; u < 8; ++u) {
            int e = ebase + u * 512 + t;
            bool ok = (e < N_EDGES);
            int   r = ok ? er[e] : 0;
            int   c = ok ? ec[e] : 0;
            float v = ok ? ev[e] : 0.f;
            bkt[u] = ok ? (r >> 6) : -1;
            pk[u]  = make_uint2(((unsigned)(r & 63) << 16) | (unsigned)c,
                                __float_as_int(v));
            if (ok) rnk[u] = atomicAdd(&hist[r >> 6], 1);   // LDS int atomic
        }
        __syncthreads();
        for (int i = t; i < NBUCK; i += 512) {
            int h = hist[i];
            base[i] = h ? atomicAdd(&gcnt[i * GSTR], h) : 0; // line-private atomic
        }
        __syncthreads();
#pragma unroll
        for (int u = 0; u < 8; ++u) {
            if (bkt[u] >= 0) {
                int pos = base[bkt[u]] + rnk[u];
                if (pos < BCAP)
                    bedge[(size_t)bkt[u] * BCAP + pos] = pk[u];
            }
        }
        return;
    }

    const int gbid = blockIdx.x - SCATTER_BLOCKS;       // 0..781
    const int half = gbid / GEMM_MBLKS;                 // 0 or 1
    const int mblk = gbid % GEMM_MBLKS;
    const int wave = t >> 6, lane = t & 63;
    const int quad = lane >> 4, l16 = lane & 15;
    const int m0   = mblk * 128;
    const int n0   = half * 128;

    const int grow = m0 + wave * 16 + l16;              // this lane's A row
    const int arow = grow < N_NODES ? grow : 0;         // clamp; results unused
    const float* aptr = &feat[(size_t)arow * D_IN + quad * 8];

    floatx4 acc[8];
#pragma unroll
    for (int nt = 0; nt < 8; ++nt)
        acc[nt] = (floatx4){0.f, 0.f, 0.f, 0.f};

    for (int kt = 0; kt < D_IN; kt += 128) {
        // ---- stage B (128 n-rows x 128 k) from L2-hot Wb[n][k] ----
#pragma unroll
        for (int i = 0; i < 8; ++i) {
            int g = t + i * 512;          // 0..4095
            int row = g >> 4, kq = g & 15;
            *(uint4*)&Bs[row * BPAD + kq * 8] =
                *(const uint4*)&Wb[(size_t)(n0 + row) * D_IN + kt + kq * 8];
        }
        __syncthreads();

        // ---- preload this phase's 4 A-frags (8 indep float4 in flight) ----
        const float* p = aptr + kt;
        float4 q0 = *(const float4*)(p +  0), q1 = *(const float4*)(p +  4);
        float4 q2 = *(const float4*)(p + 32), q3 = *(const float4*)(p + 36);
        float4 q4 = *(const float4*)(p + 64), q5 = *(const float4*)(p + 68);
        float4 q6 = *(const float4*)(p + 96), q7 = *(const float4*)(p + 100);
        bf16x8 a0 = packbf(q0, q1), a1 = packbf(q2, q3);
        bf16x8 a2 = packbf(q4, q5), a3 = packbf(q6, q7);

#pragma unroll
        for (int s = 0; s < 4; ++s) {
            bf16x8 a = (s == 0) ? a0 : (s == 1) ? a1 : (s == 2) ? a2 : a3;
            const int kk = s * 32;
            bf16x8 b[8];
#pragma unroll
            for (int nt = 0; nt < 8; ++nt)
                b[nt] = *(bf16x8*)&Bs[(nt * 16 + l16) * BPAD + kk + quad * 8];
#pragma unroll
            for (int nt = 0; nt < 8; ++nt)
                acc[nt] = __builtin_amdgcn_mfma_f32_16x16x32_bf16(
                    a, b[nt], acc[nt], 0, 0, 0);
        }
        __syncthreads();
    }

    if (half == 0) {
        float bb[8], sc[8], of[8];
#pragma unroll
        for (int nt = 0; nt < 8; ++nt) {
            bb[nt] = bias[nt * 16 + l16];
            sc[nt] = scale[nt * 16 + l16];
            of[nt] = offset[nt * 16 + l16];
        }
#pragma unroll
        for (int i = 0; i < 4; ++i) {
            float h[8], s = 0.f, q = 0.f;
#pragma unroll
            for (int nt = 0; nt < 8; ++nt) {
                h[nt] = fmaxf(acc[nt][i] + bb[nt], 0.f);
                s += h[nt];
                q += h[nt] * h[nt];
            }
#pragma unroll
            for (int m = 1; m < 16; m <<= 1) {
                s += __shfl_xor(s, m);
                q += __shfl_xor(q, m);
            }
            float mean = s * (1.f / 128.f);
            float inv  = rsqrtf(q * (1.f / 128.f) - mean * mean + EPS);
            int row = m0 + wave * 16 + quad * 4 + i;
            if (row < N_NODES) {
#pragma unroll
                for (int nt = 0; nt < 8; ++nt)
                    out[(size_t)row * 256 + nt * 16 + l16] =
                        (h[nt] - mean) * sc[nt] * inv + of[nt];
            }
        }
    } else {
#pragma unroll
        for (int i = 0; i < 4; ++i) {
            int row = m0 + wave * 16 + quad * 4 + i;
            if (row < N_NODES) {
#pragma unroll
                for (int nt = 0; nt < 8; ++nt)
                    Y1[(size_t)row * D_OUT + nt * 16 + l16] =
                        f2bf(acc[nt][i]);
            }
        }
    }
}

// ---------------------------------------------------------------------------
// One block per bucket (64 rows, ~1024 edges), 512 threads (8 waves).
// ONE-pass CSR build (unchanged). Gather: PAIR-EDGE scheme — lanes 0-31
// process even edges, lanes 32-63 odd edges; each lane loads uint2 (8B =
// 4 cols) per edge, so one wave covers 2 edges per VMEM instruction (half
// the instruction count of the 4B-per-lane scheme at same bytes). Halves
// combined with one shfl_xor(32); LN reduce is 5 steps; coalesced float4
// stores -> out[:, 128:256].
// ---------------------------------------------------------------------------
__global__ __launch_bounds__(512) void spmm_csr_ln(
    const int* __restrict__ gcnt, const uint2* __restrict__ bedge,
    const ushort* __restrict__ Y,
    const float* __restrict__ bias, const float* __restrict__ scale,
    const float* __restrict__ offset, float* __restrict__ out)
{
    __shared__ ushort lcol[BCAP];
    __shared__ float  lval[BCAP];
    __shared__ int    cnt[RPB];
    __shared__ int    offx[RPB];

    const int t      = threadIdx.x;
    const int bucket = blockIdx.x;
    const int r0     = bucket * RPB;
    const int nrows  = min(RPB, N_NODES - r0);
    int ne = gcnt[bucket * GSTR];
    ne = ne < BCAP ? ne : BCAP;

    if (t < RPB) cnt[t] = 0;
    __syncthreads();

    // ---- count pass (single bedge read; edges parked in named regs) ----
    const size_t base = (size_t)bucket * BCAP;
    int   erA = -1, erB = -1, erC = -1;
    int   ecA = 0,  ecB = 0,  ecC = 0;
    float evA = 0.f, evB = 0.f, evC = 0.f;
    int   rkA = 0,  rkB = 0,  rkC = 0;
    if (t < ne) {
        uint2 p = bedge[base + t];
        erA = (int)(p.x >> 16); ecA = (int)(p.x & 0xffffu);
        evA = __uint_as_float(p.y);
        rkA = atomicAdd(&cnt[erA], 1);
    }
    if (t + 512 < ne) {
        uint2 p = bedge[base + t + 512];
        erB = (int)(p.x >> 16); ecB = (int)(p.x & 0xffffu);
        evB = __uint_as_float(p.y);
        rkB = atomicAdd(&cnt[erB], 1);
    }
    if (t + 1024 < ne) {
        uint2 p = bedge[base + t + 1024];
        erC = (int)(p.x >> 16); ecC = (int)(p.x & 0xffffu);
        evC = __uint_as_float(p.y);
        rkC = atomicAdd(&cnt[erC], 1);
    }
    __syncthreads();

    // ---- exclusive prefix over 64 counts, wave 0 via shfl ----
    if (t < RPB) {
        int c = cnt[t], x = c;
#pragma unroll
        for (int s = 1; s < RPB; s <<= 1) {
            int w = __shfl_up(x, s);
            if (t >= s) x += w;
        }
        offx[t] = x - c;
    }
    __syncthreads();

    // ---- place from registers ----
    if (erA >= 0) { int k = offx[erA] + rkA; lcol[k] = (ushort)ecA; lval[k] = evA; }
    if (erB >= 0) { int k = offx[erB] + rkB; lcol[k] = (ushort)ecB; lval[k] = evB; }
    if (erC >= 0) { int k = offx[erC] + rkC; lcol[k] = (ushort)ecC; lval[k] = evC; }
    __syncthreads();

    // ---- pair-edge wave-per-row gather + LN ----
    const int wave = t >> 6, lane = t & 63;
    const int eh   = lane >> 5;          // 0: even edges, 1: odd edges
    const int l32  = lane & 31;
    const int c0   = l32 * 4;            // this lane's 4 columns
    const float4 bb = *(const float4*)&bias[c0];
    const float4 ss = *(const float4*)&scale[c0];
    const float4 oo = *(const float4*)&offset[c0];

    for (int ri = wave; ri < nrows; ri += 8) {
        int beg = offx[ri], n = cnt[ri];
        float a0 = 0.f, a1 = 0.f, a2 = 0.f, a3 = 0.f;
        int j = 0;
        for (; j + 16 <= n; j += 16) {
            uint2 yv[8]; float vv[8];
#pragma unroll
            for (int u = 0; u < 8; ++u) {
                int idx = beg + j + u * 2 + eh;
                int c   = lcol[idx];
                vv[u]   = lval[idx];
                yv[u]   = *(const uint2*)&Y[(size_t)c * D_OUT + c0];
            }
#pragma unroll
            for (int u = 0; u < 8; ++u) {
                a0 = fmaf(vv[u], __uint_as_float(yv[u].x << 16), a0);
                a1 = fmaf(vv[u], __uint_as_float(yv[u].x & 0xffff0000u), a1);
                a2 = fmaf(vv[u], __uint_as_float(yv[u].y << 16), a2);
                a3 = fmaf(vv[u], __uint_as_float(yv[u].y & 0xffff0000u), a3);
            }
        }
        for (; j < n; j += 2) {
            int  jj = j + eh;
            bool ok = jj < n;
            int idx = beg + jj; idx = idx < BCAP ? idx : BCAP - 1;
            int   c = lcol[idx];
            float v = ok ? lval[idx] : 0.f;
            uint2 yv = *(const uint2*)&Y[(size_t)c * D_OUT + c0];
            a0 = fmaf(v, __uint_as_float(yv.x << 16), a0);
            a1 = fmaf(v, __uint_as_float(yv.x & 0xffff0000u), a1);
            a2 = fmaf(v, __uint_as_float(yv.y << 16), a2);
            a3 = fmaf(v, __uint_as_float(yv.y & 0xffff0000u), a3);
        }
        // combine even/odd halves: lanes l and l^32 hold same col-group
        a0 += __shfl_xor(a0, 32);
        a1 += __shfl_xor(a1, 32);
        a2 += __shfl_xor(a2, 32);
        a3 += __shfl_xor(a3, 32);

        float h0 = fmaxf(a0 + bb.x, 0.f);
        float h1 = fmaxf(a1 + bb.y, 0.f);
        float h2 = fmaxf(a2 + bb.z, 0.f);
        float h3 = fmaxf(a3 + bb.w, 0.f);
        float s = h0 + h1 + h2 + h3;
        float q = h0 * h0 + h1 * h1 + h2 * h2 + h3 * h3;
#pragma unroll
        for (int m = 1; m < 32; m <<= 1) {
            s += __shfl_xor(s, m);
            q += __shfl_xor(q, m);
        }
        float mean = s * (1.f / 128.f);
        float inv  = rsqrtf(q * (1.f / 128.f) - mean * mean + EPS);
        if (eh == 0) {
            int row = r0 + ri;
            float4 o;
            o.x = (h0 - mean) * ss.x * inv + oo.x;
            o.y = (h1 - mean) * ss.y * inv + oo.y;
            o.z = (h2 - mean) * ss.z * inv + oo.z;
            o.w = (h3 - mean) * ss.w * inv + oo.w;
            *(float4*)&out[(size_t)row * 256 + 128 + c0] = o;
        }
    }
}

extern "C" void kernel_launch(void* const* d_in, const int* in_sizes, int n_in,
                              void* d_out, int out_size, void* d_ws, size_t ws_size,
                              hipStream_t stream)
{
    const float* feat = (const float*)d_in[0];
    const float* W0   = (const float*)d_in[1];
    const float* b0   = (const float*)d_in[2];
    const float* s0   = (const float*)d_in[3];
    const float* o0   = (const float*)d_in[4];
    const float* W1   = (const float*)d_in[5];
    const float* b1   = (const float*)d_in[6];
    const float* s1   = (const float*)d_in[7];
    const float* o1   = (const float*)d_in[8];
    const int*   er   = (const int*)d_in[9];
    const int*   ec   = (const int*)d_in[10];
    const float* ev   = (const float*)d_in[11];
    float* out = (float*)d_out;

    // workspace layout (16B-aligned offsets), total ~21.4 MB
    char*   wsb   = (char*)d_ws;
    ushort* Wb    = (ushort*)(wsb);                 //    131,072 B
    ushort* Y1    = (ushort*)(wsb + 131072);        // 12,800,000 B
    int*    gcnt  = (int*)   (wsb + 12931072);      //     50,048 B (line-padded)
    uint2*  bedge = (uint2*) (wsb + 12981248);      //  8,408,064 B

    prep_small<<<1 + WB_BLOCKS, 256, 0, stream>>>(W0, W1, Wb, gcnt);

    gemm_scatter<<<SCATTER_BLOCKS + 2 * GEMM_MBLKS, 512, 0, stream>>>(
        feat, Wb, b0, s0, o0, out, Y1, er, ec, ev, gcnt, bedge);

    spmm_csr_ln<<<NBUCK, 512, 0, stream>>>(
        gcnt, bedge, Y1, b1, s1, o1, out);
}

// Round 7
// 190.515 us; speedup vs baseline: 1.0127x; 1.0127x over previous
//
#include <hip/hip_runtime.h>

#define N_NODES 50000
#define N_EDGES 800000
#define D_IN    256
#define D_OUT   128
#define EPS     1e-9f
#define BPAD    136     // Bs k-stride in ushorts: 272B rows (16B-aligned), 2-way bank alias = free

#define SCATTER_BLOCKS 196   // 196 * 4096 = 802816 >= 800000 edges
#define GEMM_MBLKS     391   // ceil(50000/128)

// bucket scatter: rows grouped 64/bucket; global atomics only per (block,bucket)
#define RPB    64
#define NBUCK  782           // ceil(50000/64)
#define BCAP   1344          // mean 1024 + 10 sigma; overflow ~impossible
#define GSTR   16            // gcnt stride in ints: one bucket per 64B line

typedef __attribute__((ext_vector_type(8))) short bf16x8;   // MFMA A/B frag (4 VGPRs)
typedef __attribute__((ext_vector_type(4))) float floatx4;  // MFMA C/D frag

__device__ __forceinline__ ushort f2bf(float x) {           // RTNE fp32 -> bf16
    unsigned u = __float_as_uint(x);
    u += 0x7fffu + ((u >> 16) & 1u);
    return (ushort)(u >> 16);
}

__device__ __forceinline__ bf16x8 packbf(float4 a, float4 b) {
    union { ushort us[8]; bf16x8 v; } r;
    r.us[0] = f2bf(a.x); r.us[1] = f2bf(a.y);
    r.us[2] = f2bf(a.z); r.us[3] = f2bf(a.w);
    r.us[4] = f2bf(b.x); r.us[5] = f2bf(b.y);
    r.us[6] = f2bf(b.z); r.us[7] = f2bf(b.w);
    return r.v;
}

// ---------------------------------------------------------------------------
// prep_small: (a) gcnt[NBUCK*GSTR] = 0  (b) Wb[n][k] = bf16 transposed [W0|W1].
// ---------------------------------------------------------------------------
#define WB_BLOCKS  32
__global__ __launch_bounds__(256) void prep_small(
    const float* __restrict__ W0, const float* __restrict__ W1,
    ushort* __restrict__ Wb, int* __restrict__ gcnt)
{
    int bid = blockIdx.x;
    int t   = threadIdx.x;
    if (bid == 0) {
        for (int i = t; i < NBUCK * GSTR; i += 256) gcnt[i] = 0;
    } else {
        int g  = (bid - 1) * 256 + t;
        int n  = g >> 5;                      // 0..255
        int kq = g & 31;                      // 8-elem k group
        const float* W = (n < 128) ? W0 : W1;
        int nn = n & 127;
        union { ushort us[8]; uint4 v; } tmp;
#pragma unroll
        for (int j = 0; j < 8; ++j)
            tmp.us[j] = f2bf(W[(size_t)(kq * 8 + j) * D_OUT + nn]);
        *(uint4*)&Wb[(size_t)n * D_IN + kq * 8] = tmp.v;
    }
}

// ---------------------------------------------------------------------------
// Fused kernel, BLOCK-role split, 512 threads.
//   bid < SCATTER_BLOCKS: LDS-aggregated bucket scatter of 4096 edges
//     (8/thread). LDS int atomics for ranks; one global atomicAdd per touched
//     (block,bucket) reserves a contiguous bedge range (gcnt line-padded).
//   else: 128(M) x 128(N) gemm tile, 8 waves, each wave owns 16 rows.
//     A: global->register direct; B: LDS, two K=128 phases.
//     half 0: cols 0..127  -> bias0+relu+LN -> out[:, 0:128]
//     half 1: cols 128..255 -> raw bf16 -> Y1[M,128]
// ---------------------------------------------------------------------------
__global__ __launch_bounds__(512, 4) void gemm_scatter(
    const float* __restrict__ feat, const ushort* __restrict__ Wb,
    const float* __restrict__ bias, const float* __restrict__ scale,
    const float* __restrict__ offset,
    float* __restrict__ out, ushort* __restrict__ Y1,
    const int* __restrict__ er, const int* __restrict__ ec,
    const float* __restrict__ ev, int* __restrict__ gcnt,
    uint2* __restrict__ bedge)
{
    __shared__ __align__(16) ushort Bs[128 * BPAD];   // 34816 B

    const int t = threadIdx.x;

    if (blockIdx.x < SCATTER_BLOCKS) {
        int* hist = (int*)Bs;          // NBUCK ints
        int* base = hist + NBUCK;      // NBUCK ints (6.3KB total, fits)
        for (int i = t; i < NBUCK; i += 512) hist[i] = 0;
        __syncthreads();

        int ebase = blockIdx.x * 4096;
        int   bkt[8], rnk[8];
        uint2 pk[8];
#pragma unroll
        for (int u = 0; u < 8; ++u) {
            int e = ebase + u * 512 + t;
            bool ok = (e < N_EDGES);
            int   r = ok ? er[e] : 0;
            int   c = ok ? ec[e] : 0;
            float v = ok ? ev[e] : 0.f;
            bkt[u] = ok ? (r >> 6) : -1;
            pk[u]  = make_uint2(((unsigned)(r & 63) << 16) | (unsigned)c,
                                __float_as_uint(v));
            if (ok) rnk[u] = atomicAdd(&hist[r >> 6], 1);   // LDS int atomic
        }
        __syncthreads();
        for (int i = t; i < NBUCK; i += 512) {
            int h = hist[i];
            base[i] = h ? atomicAdd(&gcnt[i * GSTR], h) : 0; // line-private atomic
        }
        __syncthreads();
#pragma unroll
        for (int u = 0; u < 8; ++u) {
            if (bkt[u] >= 0) {
                int pos = base[bkt[u]] + rnk[u];
                if (pos < BCAP)
                    bedge[(size_t)bkt[u] * BCAP + pos] = pk[u];
            }
        }
        return;
    }

    const int gbid = blockIdx.x - SCATTER_BLOCKS;       // 0..781
    const int half = gbid / GEMM_MBLKS;                 // 0 or 1
    const int mblk = gbid % GEMM_MBLKS;
    const int wave = t >> 6, lane = t & 63;
    const int quad = lane >> 4, l16 = lane & 15;
    const int m0   = mblk * 128;
    const int n0   = half * 128;

    const int grow = m0 + wave * 16 + l16;              // this lane's A row
    const int arow = grow < N_NODES ? grow : 0;         // clamp; results unused
    const float* aptr = &feat[(size_t)arow * D_IN + quad * 8];

    floatx4 acc[8];
#pragma unroll
    for (int nt = 0; nt < 8; ++nt)
        acc[nt] = (floatx4){0.f, 0.f, 0.f, 0.f};

    for (int kt = 0; kt < D_IN; kt += 128) {
        // ---- stage B (128 n-rows x 128 k) from L2-hot Wb[n][k] ----
#pragma unroll
        for (int i = 0; i < 8; ++i) {
            int g = t + i * 512;          // 0..4095
            int row = g >> 4, kq = g & 15;
            *(uint4*)&Bs[row * BPAD + kq * 8] =
                *(const uint4*)&Wb[(size_t)(n0 + row) * D_IN + kt + kq * 8];
        }
        __syncthreads();

        // ---- preload this phase's 4 A-frags (8 indep float4 in flight) ----
        const float* p = aptr + kt;
        float4 q0 = *(const float4*)(p +  0), q1 = *(const float4*)(p +  4);
        float4 q2 = *(const float4*)(p + 32), q3 = *(const float4*)(p + 36);
        float4 q4 = *(const float4*)(p + 64), q5 = *(const float4*)(p + 68);
        float4 q6 = *(const float4*)(p + 96), q7 = *(const float4*)(p + 100);
        bf16x8 a0 = packbf(q0, q1), a1 = packbf(q2, q3);
        bf16x8 a2 = packbf(q4, q5), a3 = packbf(q6, q7);

#pragma unroll
        for (int s = 0; s < 4; ++s) {
            bf16x8 a = (s == 0) ? a0 : (s == 1) ? a1 : (s == 2) ? a2 : a3;
            const int kk = s * 32;
            bf16x8 b[8];
#pragma unroll
            for (int nt = 0; nt < 8; ++nt)
                b[nt] = *(bf16x8*)&Bs[(nt * 16 + l16) * BPAD + kk + quad * 8];
#pragma unroll
            for (int nt = 0; nt < 8; ++nt)
                acc[nt] = __builtin_amdgcn_mfma_f32_16x16x32_bf16(
                    a, b[nt], acc[nt], 0, 0, 0);
        }
        __syncthreads();
    }

    if (half == 0) {
        float bb[8], sc[8], of[8];
#pragma unroll
        for (int nt = 0; nt < 8; ++nt) {
            bb[nt] = bias[nt * 16 + l16];
            sc[nt] = scale[nt * 16 + l16];
            of[nt] = offset[nt * 16 + l16];
        }
#pragma unroll
        for (int i = 0; i < 4; ++i) {
            float h[8], s = 0.f, q = 0.f;
#pragma unroll
            for (int nt = 0; nt < 8; ++nt) {
                h[nt] = fmaxf(acc[nt][i] + bb[nt], 0.f);
                s += h[nt];
                q += h[nt] * h[nt];
            }
#pragma unroll
            for (int m = 1; m < 16; m <<= 1) {
                s += __shfl_xor(s, m);
                q += __shfl_xor(q, m);
            }
            float mean = s * (1.f / 128.f);
            float inv  = rsqrtf(q * (1.f / 128.f) - mean * mean + EPS);
            int row = m0 + wave * 16 + quad * 4 + i;
            if (row < N_NODES) {
#pragma unroll
                for (int nt = 0; nt < 8; ++nt)
                    out[(size_t)row * 256 + nt * 16 + l16] =
                        (h[nt] - mean) * sc[nt] * inv + of[nt];
            }
        }
    } else {
#pragma unroll
        for (int i = 0; i < 4; ++i) {
            int row = m0 + wave * 16 + quad * 4 + i;
            if (row < N_NODES) {
#pragma unroll
                for (int nt = 0; nt < 8; ++nt)
                    Y1[(size_t)row * D_OUT + nt * 16 + l16] =
                        f2bf(acc[nt][i]);
            }
        }
    }
}

// ---------------------------------------------------------------------------
// One block per bucket (64 rows, ~1024 edges), 512 threads (8 waves).
// ONE-pass CSR build (unchanged, proven). Gather: wave-per-row, 4B/lane
// whole-row reads, ceil(n/16) FULLY-PREDICATED batches of 16 loads —
// out-of-range slots clamp idx to beg (cached row, near-free) with weight 0.
// Every row keeps 16 independent VMEM ops in flight; NO serial tail loop
// (R5's pair-edge tail serialized 53% of rows -> +13us regression).
// Then bias+relu+LN -> out[:, 128:256].
// ---------------------------------------------------------------------------
__global__ __launch_bounds__(512) void spmm_csr_ln(
    const int* __restrict__ gcnt, const uint2* __restrict__ bedge,
    const ushort* __restrict__ Y,
    const float* __restrict__ bias, const float* __restrict__ scale,
    const float* __restrict__ offset, float* __restrict__ out)
{
    __shared__ ushort lcol[BCAP];
    __shared__ float  lval[BCAP];
    __shared__ int    cnt[RPB];
    __shared__ int    offx[RPB];

    const int t      = threadIdx.x;
    const int bucket = blockIdx.x;
    const int r0     = bucket * RPB;
    const int nrows  = min(RPB, N_NODES - r0);
    int ne = gcnt[bucket * GSTR];
    ne = ne < BCAP ? ne : BCAP;

    if (t < RPB) cnt[t] = 0;
    __syncthreads();

    // ---- count pass (single bedge read; edges parked in named regs) ----
    const size_t base = (size_t)bucket * BCAP;
    int   erA = -1, erB = -1, erC = -1;
    int   ecA = 0,  ecB = 0,  ecC = 0;
    float evA = 0.f, evB = 0.f, evC = 0.f;
    int   rkA = 0,  rkB = 0,  rkC = 0;
    if (t < ne) {
        uint2 p = bedge[base + t];
        erA = (int)(p.x >> 16); ecA = (int)(p.x & 0xffffu);
        evA = __uint_as_float(p.y);
        rkA = atomicAdd(&cnt[erA], 1);
    }
    if (t + 512 < ne) {
        uint2 p = bedge[base + t + 512];
        erB = (int)(p.x >> 16); ecB = (int)(p.x & 0xffffu);
        evB = __uint_as_float(p.y);
        rkB = atomicAdd(&cnt[erB], 1);
    }
    if (t + 1024 < ne) {
        uint2 p = bedge[base + t + 1024];
        erC = (int)(p.x >> 16); ecC = (int)(p.x & 0xffffu);
        evC = __uint_as_float(p.y);
        rkC = atomicAdd(&cnt[erC], 1);
    }
    __syncthreads();

    // ---- exclusive prefix over 64 counts, wave 0 via shfl ----
    if (t < RPB) {
        int c = cnt[t], x = c;
#pragma unroll
        for (int s = 1; s < RPB; s <<= 1) {
            int w = __shfl_up(x, s);
            if (t >= s) x += w;
        }
        offx[t] = x - c;
    }
    __syncthreads();

    // ---- place from registers ----
    if (erA >= 0) { int k = offx[erA] + rkA; lcol[k] = (ushort)ecA; lval[k] = evA; }
    if (erB >= 0) { int k = offx[erB] + rkB; lcol[k] = (ushort)ecB; lval[k] = evB; }
    if (erC >= 0) { int k = offx[erC] + rkC; lcol[k] = (ushort)ecC; lval[k] = evC; }
    __syncthreads();

    // ---- wave-per-row gather + LN ----
    const int wave = t >> 6, lane = t & 63;
    const int cidx = lane * 2;
    const float b0v = bias[cidx],   b1v = bias[cidx + 1];
    const float s0v = scale[cidx],  s1v = scale[cidx + 1];
    const float o0v = offset[cidx], o1v = offset[cidx + 1];

    for (int ri = wave; ri < nrows; ri += 8) {
        int beg = offx[ri], n = cnt[ri];
        float ax = 0.f, ay = 0.f;
        for (int j = 0; j < n; j += 16) {
            unsigned yv[16]; float vv[16];
#pragma unroll
            for (int u = 0; u < 16; ++u) {
                int jj  = j + u;
                bool ok = jj < n;
                int idx = beg + (ok ? jj : 0);         // clamp: wasted loads hit cached beg-row
                int c   = lcol[idx];                   // LDS broadcast
                vv[u]   = ok ? lval[idx] : 0.f;
                yv[u]   = *(const unsigned*)&Y[(size_t)c * D_OUT + cidx];
            }
#pragma unroll
            for (int u = 0; u < 16; ++u) {
                ax = fmaf(vv[u], __uint_as_float(yv[u] << 16), ax);
                ay = fmaf(vv[u], __uint_as_float(yv[u] & 0xffff0000u), ay);
            }
        }
        float h0 = fmaxf(ax + b0v, 0.f);
        float h1 = fmaxf(ay + b1v, 0.f);
        float s = h0 + h1, q = h0 * h0 + h1 * h1;
#pragma unroll
        for (int m = 1; m < 64; m <<= 1) {
            s += __shfl_xor(s, m);
            q += __shfl_xor(q, m);
        }
        float mean = s * (1.f / 128.f);
        float inv  = rsqrtf(q * (1.f / 128.f) - mean * mean + EPS);
        int row = r0 + ri;
        float2 o;
        o.x = (h0 - mean) * s0v * inv + o0v;
        o.y = (h1 - mean) * s1v * inv + o1v;
        *(float2*)&out[(size_t)row * 256 + 128 + cidx] = o;
    }
}

extern "C" void kernel_launch(void* const* d_in, const int* in_sizes, int n_in,
                              void* d_out, int out_size, void* d_ws, size_t ws_size,
                              hipStream_t stream)
{
    const float* feat = (const float*)d_in[0];
    const float* W0   = (const float*)d_in[1];
    const float* b0   = (const float*)d_in[2];
    const float* s0   = (const float*)d_in[3];
    const float* o0   = (const float*)d_in[4];
    const float* W1   = (const float*)d_in[5];
    const float* b1   = (const float*)d_in[6];
    const float* s1   = (const float*)d_in[7];
    const float* o1   = (const float*)d_in[8];
    const int*   er   = (const int*)d_in[9];
    const int*   ec   = (const int*)d_in[10];
    const float* ev   = (const float*)d_in[11];
    float* out = (float*)d_out;

    // workspace layout (16B-aligned offsets), total ~21.4 MB
    char*   wsb   = (char*)d_ws;
    ushort* Wb    = (ushort*)(wsb);                 //    131,072 B
    ushort* Y1    = (ushort*)(wsb + 131072);        // 12,800,000 B
    int*    gcnt  = (int*)   (wsb + 12931072);      //     50,048 B (line-padded)
    uint2*  bedge = (uint2*) (wsb + 12981248);      //  8,408,064 B

    prep_small<<<1 + WB_BLOCKS, 256, 0, stream>>>(W0, W1, Wb, gcnt);

    gemm_scatter<<<SCATTER_BLOCKS + 2 * GEMM_MBLKS, 512, 0, stream>>>(
        feat, Wb, b0, s0, o0, out, Y1, er, ec, ev, gcnt, bedge);

    spmm_csr_ln<<<NBUCK, 512, 0, stream>>>(
        gcnt, bedge, Y1, b1, s1, o1, out);
}

// Round 8
// 173.886 us; speedup vs baseline: 1.1096x; 1.0956x over previous
//
#include <hip/hip_runtime.h>

#define N_NODES 50000
#define N_EDGES 800000
#define D_IN    256
#define D_OUT   128
#define EPS     1e-9f
#define BPAD    136     // Bs k-stride in ushorts: 272B rows (16B-aligned), 2-way bank alias = free

#define SCATTER_BLOCKS 196   // 196 * 4096 = 802816 >= 800000 edges
#define GEMM_MBLKS     391   // ceil(50000/128)

// bucket scatter: rows grouped 64/bucket; global atomics only per (block,bucket)
#define RPB    64
#define NBUCK  782           // ceil(50000/64)
#define BCAP   1344          // mean 1024 + 10 sigma; overflow ~impossible
#define GSTR   16            // gcnt stride in ints: one bucket per 64B line
#define LCAP   1792          // BCAP + 64*7: per-row pad-to-8 worst case

// fused-kernel shared memory union (scatter branch needs 42.3KB, gemm 34.8KB)
#define SORT_OFF  0          // uint2 sorted[4096]           32768 B
#define HIST_OFF  32768      // int hist[NBUCK]               3128 B
#define LOFF_OFF  35896      // int loff[NBUCK]               3128 B
#define BASE_OFF  39024      // int base[NBUCK]               3128 B
#define CSUM_OFF  42152      // int csum[16]                    64 B
#define CBAS_OFF  42216      // int cbas[16]                    64 B
#define SMEM_BYTES 42280

typedef __attribute__((ext_vector_type(8))) short bf16x8;   // MFMA A/B frag (4 VGPRs)
typedef __attribute__((ext_vector_type(4))) float floatx4;  // MFMA C/D frag

__device__ __forceinline__ ushort f2bf(float x) {           // RTNE fp32 -> bf16
    unsigned u = __float_as_uint(x);
    u += 0x7fffu + ((u >> 16) & 1u);
    return (ushort)(u >> 16);
}

__device__ __forceinline__ bf16x8 packbf(float4 a, float4 b) {
    union { ushort us[8]; bf16x8 v; } r;
    r.us[0] = f2bf(a.x); r.us[1] = f2bf(a.y);
    r.us[2] = f2bf(a.z); r.us[3] = f2bf(a.w);
    r.us[4] = f2bf(b.x); r.us[5] = f2bf(b.y);
    r.us[6] = f2bf(b.z); r.us[7] = f2bf(b.w);
    return r.v;
}

// ---------------------------------------------------------------------------
// prep_small: (a) gcnt[NBUCK*GSTR] = 0  (b) Wb[n][k] = bf16 transposed [W0|W1].
// ---------------------------------------------------------------------------
#define WB_BLOCKS  32
__global__ __launch_bounds__(256) void prep_small(
    const float* __restrict__ W0, const float* __restrict__ W1,
    ushort* __restrict__ Wb, int* __restrict__ gcnt)
{
    int bid = blockIdx.x;
    int t   = threadIdx.x;
    if (bid == 0) {
        for (int i = t; i < NBUCK * GSTR; i += 256) gcnt[i] = 0;
    } else {
        int g  = (bid - 1) * 256 + t;
        int n  = g >> 5;                      // 0..255
        int kq = g & 31;                      // 8-elem k group
        const float* W = (n < 128) ? W0 : W1;
        int nn = n & 127;
        union { ushort us[8]; uint4 v; } tmp;
#pragma unroll
        for (int j = 0; j < 8; ++j)
            tmp.us[j] = f2bf(W[(size_t)(kq * 8 + j) * D_OUT + nn]);
        *(uint4*)&Wb[(size_t)n * D_IN + kq * 8] = tmp.v;
    }
}

// ---------------------------------------------------------------------------
// Fused kernel, BLOCK-role split, 512 threads.
//   bid < SCATTER_BLOCKS: bucket scatter of 4096 edges with BLOCK-LOCAL
//     COUNTING SORT. R4-R7 evidence: random-line bedge writes (~800K line-ops
//     @ ~15-20G/s) were the fused kernel's critical path (~43us invariant
//     under GEMM restructures). Sort edges by bucket in LDS (rank atomics +
//     block-wide scan of hist[782]), then write sorted runs: consecutive
//     lanes -> consecutive addresses -> ~4x fewer line-ops.
//     Edge pk = bkt<<22 | rowlow6<<16 | col16 (782 < 1024 fits 10 bits).
//   else: 128(M) x 128(N) gemm tile, 8 waves; A global->reg direct, B in LDS.
//     half 0: cols 0..127  -> bias0+relu+LN -> out[:, 0:128]
//     half 1: cols 128..255 -> raw bf16 -> Y1[M,128]
// ---------------------------------------------------------------------------
__global__ __launch_bounds__(512, 4) void gemm_scatter(
    const float* __restrict__ feat, const ushort* __restrict__ Wb,
    const float* __restrict__ bias, const float* __restrict__ scale,
    const float* __restrict__ offset,
    float* __restrict__ out, ushort* __restrict__ Y1,
    const int* __restrict__ er, const int* __restrict__ ec,
    const float* __restrict__ ev, int* __restrict__ gcnt,
    uint2* __restrict__ bedge)
{
    __shared__ __align__(16) char smem[SMEM_BYTES];

    const int t = threadIdx.x;

    if (blockIdx.x < SCATTER_BLOCKS) {
        uint2* sorted = (uint2*)(smem + SORT_OFF);
        int*   hist   = (int*)(smem + HIST_OFF);
        int*   loff   = (int*)(smem + LOFF_OFF);
        int*   base   = (int*)(smem + BASE_OFF);
        int*   csum   = (int*)(smem + CSUM_OFF);
        int*   cbas   = (int*)(smem + CBAS_OFF);

        for (int i = t; i < NBUCK; i += 512) hist[i] = 0;
        __syncthreads();

        const int ebase  = blockIdx.x * 4096;
        const int ecount = min(4096, N_EDGES - ebase);
        int   bkt[8], rnk[8];
        uint2 pk[8];
#pragma unroll
        for (int u = 0; u < 8; ++u) {
            int e = ebase + u * 512 + t;
            bool ok = (e < N_EDGES);
            int   r = ok ? er[e] : 0;
            int   c = ok ? ec[e] : 0;
            float v = ok ? ev[e] : 0.f;
            int   b = r >> 6;
            bkt[u] = ok ? b : -1;
            pk[u]  = make_uint2(((unsigned)b << 22) |
                                ((unsigned)(r & 63) << 16) | (unsigned)c,
                                __float_as_uint(v));
            if (ok) rnk[u] = atomicAdd(&hist[b], 1);        // LDS int atomic
        }
        __syncthreads();

        // ---- block-wide exclusive scan of hist[782] (two 512-strips) ----
        {
            const int lane = t & 63, w = t >> 6;
            int v0 = (t < NBUCK) ? hist[t] : 0;
            int x0 = v0;
#pragma unroll
            for (int s = 1; s < 64; s <<= 1) {
                int y = __shfl_up(x0, s);
                if (lane >= s) x0 += y;
            }
            if (lane == 63) csum[w] = x0;
            const int i1 = t + 512;
            int v1 = (i1 < NBUCK) ? hist[i1] : 0;
            int x1 = v1;
#pragma unroll
            for (int s = 1; s < 64; s <<= 1) {
                int y = __shfl_up(x1, s);
                if (lane >= s) x1 += y;
            }
            if (lane == 63) csum[8 + w] = x1;
            __syncthreads();
            if (t == 0) {
                int run = 0;
#pragma unroll
                for (int c = 0; c < 16; ++c) { cbas[c] = run; run += csum[c]; }
            }
            __syncthreads();
            if (t < NBUCK)  loff[t]  = x0 - v0 + cbas[w];
            if (i1 < NBUCK) loff[i1] = x1 - v1 + cbas[8 + w];
        }
        __syncthreads();

        // ---- place into bucket-sorted LDS array ----
#pragma unroll
        for (int u = 0; u < 8; ++u) {
            if (bkt[u] >= 0)
                sorted[loff[bkt[u]] + rnk[u]] = pk[u];
        }
        // ---- reserve global ranges (line-private gcnt atomics) ----
        for (int i = t; i < NBUCK; i += 512) {
            int h = hist[i];
            base[i] = h ? atomicAdd(&gcnt[i * GSTR], h) : 0;
        }
        __syncthreads();

        // ---- coalesced-run writeout: lanes cover consecutive sorted k ----
#pragma unroll
        for (int u = 0; u < 8; ++u) {
            int k = t + u * 512;
            if (k < ecount) {
                uint2 e = sorted[k];
                int b   = (int)(e.x >> 22);
                int pos = base[b] + (k - loff[b]);
                if (pos < BCAP)
                    bedge[(size_t)b * BCAP + pos] = e;
            }
        }
        return;
    }

    const int gbid = blockIdx.x - SCATTER_BLOCKS;       // 0..781
    const int half = gbid / GEMM_MBLKS;                 // 0 or 1
    const int mblk = gbid % GEMM_MBLKS;
    const int wave = t >> 6, lane = t & 63;
    const int quad = lane >> 4, l16 = lane & 15;
    const int m0   = mblk * 128;
    const int n0   = half * 128;
    ushort* Bs = (ushort*)smem;

    const int grow = m0 + wave * 16 + l16;              // this lane's A row
    const int arow = grow < N_NODES ? grow : 0;         // clamp; results unused
    const float* aptr = &feat[(size_t)arow * D_IN + quad * 8];

    floatx4 acc[8];
#pragma unroll
    for (int nt = 0; nt < 8; ++nt)
        acc[nt] = (floatx4){0.f, 0.f, 0.f, 0.f};

    for (int kt = 0; kt < D_IN; kt += 128) {
        // ---- stage B (128 n-rows x 128 k) from L2-hot Wb[n][k] ----
#pragma unroll
        for (int i = 0; i < 8; ++i) {
            int g = t + i * 512;          // 0..4095
            int row = g >> 4, kq = g & 15;
            *(uint4*)&Bs[row * BPAD + kq * 8] =
                *(const uint4*)&Wb[(size_t)(n0 + row) * D_IN + kt + kq * 8];
        }
        __syncthreads();

        // ---- preload this phase's 4 A-frags (8 indep float4 in flight) ----
        const float* p = aptr + kt;
        float4 q0 = *(const float4*)(p +  0), q1 = *(const float4*)(p +  4);
        float4 q2 = *(const float4*)(p + 32), q3 = *(const float4*)(p + 36);
        float4 q4 = *(const float4*)(p + 64), q5 = *(const float4*)(p + 68);
        float4 q6 = *(const float4*)(p + 96), q7 = *(const float4*)(p + 100);
        bf16x8 a0 = packbf(q0, q1), a1 = packbf(q2, q3);
        bf16x8 a2 = packbf(q4, q5), a3 = packbf(q6, q7);

#pragma unroll
        for (int s = 0; s < 4; ++s) {
            bf16x8 a = (s == 0) ? a0 : (s == 1) ? a1 : (s == 2) ? a2 : a3;
            const int kk = s * 32;
            bf16x8 b[8];
#pragma unroll
            for (int nt = 0; nt < 8; ++nt)
                b[nt] = *(bf16x8*)&Bs[(nt * 16 + l16) * BPAD + kk + quad * 8];
#pragma unroll
            for (int nt = 0; nt < 8; ++nt)
                acc[nt] = __builtin_amdgcn_mfma_f32_16x16x32_bf16(
                    a, b[nt], acc[nt], 0, 0, 0);
        }
        __syncthreads();
    }

    if (half == 0) {
        float bb[8], sc[8], of[8];
#pragma unroll
        for (int nt = 0; nt < 8; ++nt) {
            bb[nt] = bias[nt * 16 + l16];
            sc[nt] = scale[nt * 16 + l16];
            of[nt] = offset[nt * 16 + l16];
        }
#pragma unroll
        for (int i = 0; i < 4; ++i) {
            float h[8], s = 0.f, q = 0.f;
#pragma unroll
            for (int nt = 0; nt < 8; ++nt) {
                h[nt] = fmaxf(acc[nt][i] + bb[nt], 0.f);
                s += h[nt];
                q += h[nt] * h[nt];
            }
#pragma unroll
            for (int m = 1; m < 16; m <<= 1) {
                s += __shfl_xor(s, m);
                q += __shfl_xor(q, m);
            }
            float mean = s * (1.f / 128.f);
            float inv  = rsqrtf(q * (1.f / 128.f) - mean * mean + EPS);
            int row = m0 + wave * 16 + quad * 4 + i;
            if (row < N_NODES) {
#pragma unroll
                for (int nt = 0; nt < 8; ++nt)
                    out[(size_t)row * 256 + nt * 16 + l16] =
                        (h[nt] - mean) * sc[nt] * inv + of[nt];
            }
        }
    } else {
#pragma unroll
        for (int i = 0; i < 4; ++i) {
            int row = m0 + wave * 16 + quad * 4 + i;
            if (row < N_NODES) {
#pragma unroll
                for (int nt = 0; nt < 8; ++nt)
                    Y1[(size_t)row * D_OUT + nt * 16 + l16] =
                        f2bf(acc[nt][i]);
            }
        }
    }
}

// ---------------------------------------------------------------------------
// One block per bucket (64 rows, ~1024 edges), 512 threads (8 waves).
// ONE-pass CSR build with PAD-TO-8 rows: entries stored as {col*256, val_f32}
// uint2 in LDS; per-row counts rounded up to x8 with {0,0} dummies (read
// Y[0]*0.0, L1-hot, zero predication). Inner loop = 4 wave-instrs/edge:
// ds_read_b64 + v_add(32-bit offset) + global_load_dword + 2 unpack/2 fma.
// R7 showed 45% VALUBusy from predication/addressing — this strips it.
// Then bias+relu+LN -> out[:, 128:256].
// ---------------------------------------------------------------------------
__global__ __launch_bounds__(512) void spmm_csr_ln(
    const int* __restrict__ gcnt, const uint2* __restrict__ bedge,
    const ushort* __restrict__ Y,
    const float* __restrict__ bias, const float* __restrict__ scale,
    const float* __restrict__ offset, float* __restrict__ out)
{
    __shared__ uint2 lds_e[LCAP];
    __shared__ int   cnt[RPB];
    __shared__ int   offx[RPB];
    __shared__ int   cntp[RPB];

    const int t      = threadIdx.x;
    const int bucket = blockIdx.x;
    const int r0     = bucket * RPB;
    const int nrows  = min(RPB, N_NODES - r0);
    int ne = gcnt[bucket * GSTR];
    ne = ne < BCAP ? ne : BCAP;

    if (t < RPB) cnt[t] = 0;
    {   // zero-fill lds_e (dummy pad slots must be {0,0}): 896 uint4
        uint4* ez = (uint4*)lds_e;
        ez[t] = make_uint4(0u, 0u, 0u, 0u);
        if (t + 512 < 896) ez[t + 512] = make_uint4(0u, 0u, 0u, 0u);
    }
    __syncthreads();

    // ---- count pass (single bedge read; edges parked in named regs) ----
    const size_t base = (size_t)bucket * BCAP;
    int   erA = -1, erB = -1, erC = -1;
    unsigned exA = 0, exB = 0, exC = 0;    // col*256
    unsigned evA = 0, evB = 0, evC = 0;    // val bits
    int   rkA = 0,  rkB = 0,  rkC = 0;
    if (t < ne) {
        uint2 p = bedge[base + t];
        erA = (int)((p.x >> 16) & 63u); exA = (p.x & 0xffffu) << 8;
        evA = p.y;
        rkA = atomicAdd(&cnt[erA], 1);
    }
    if (t + 512 < ne) {
        uint2 p = bedge[base + t + 512];
        erB = (int)((p.x >> 16) & 63u); exB = (p.x & 0xffffu) << 8;
        evB = p.y;
        rkB = atomicAdd(&cnt[erB], 1);
    }
    if (t + 1024 < ne) {
        uint2 p = bedge[base + t + 1024];
        erC = (int)((p.x >> 16) & 63u); exC = (p.x & 0xffffu) << 8;
        evC = p.y;
        rkC = atomicAdd(&cnt[erC], 1);
    }
    __syncthreads();

    // ---- exclusive prefix over 64 PADDED counts, wave 0 via shfl ----
    if (t < RPB) {
        int c  = cnt[t];
        int cp = (c + 7) & ~7;
        int x  = cp;
#pragma unroll
        for (int s = 1; s < RPB; s <<= 1) {
            int w = __shfl_up(x, s);
            if (t >= s) x += w;
        }
        offx[t] = x - cp;
        cntp[t] = cp;
    }
    __syncthreads();

    // ---- place from registers ----
    if (erA >= 0) lds_e[offx[erA] + rkA] = make_uint2(exA, evA);
    if (erB >= 0) lds_e[offx[erB] + rkB] = make_uint2(exB, evB);
    if (erC >= 0) lds_e[offx[erC] + rkC] = make_uint2(exC, evC);
    __syncthreads();

    // ---- wave-per-row gather + LN ----
    const int wave  = t >> 6, lane = t & 63;
    const int lane4 = lane * 4;
    const int cidx  = lane * 2;
    const char* Yb  = (const char*)Y;
    const float b0v = bias[cidx],   b1v = bias[cidx + 1];
    const float s0v = scale[cidx],  s1v = scale[cidx + 1];
    const float o0v = offset[cidx], o1v = offset[cidx + 1];

    for (int ri = wave; ri < nrows; ri += 8) {
        int beg = offx[ri], np = cntp[ri];
        float ax = 0.f, ay = 0.f;
        for (int j = 0; j < np; j += 8) {
            uint2 e[8];
#pragma unroll
            for (int u = 0; u < 8; ++u)
                e[u] = lds_e[beg + j + u];             // LDS broadcast b64
            unsigned yv[8];
#pragma unroll
            for (int u = 0; u < 8; ++u)
                yv[u] = *(const unsigned*)(Yb + e[u].x + lane4);
#pragma unroll
            for (int u = 0; u < 8; ++u) {
                float v = __uint_as_float(e[u].y);
                ax = fmaf(v, __uint_as_float(yv[u] << 16), ax);
                ay = fmaf(v, __uint_as_float(yv[u] & 0xffff0000u), ay);
            }
        }
        float h0 = fmaxf(ax + b0v, 0.f);
        float h1 = fmaxf(ay + b1v, 0.f);
        float s = h0 + h1, q = h0 * h0 + h1 * h1;
#pragma unroll
        for (int m = 1; m < 64; m <<= 1) {
            s += __shfl_xor(s, m);
            q += __shfl_xor(q, m);
        }
        float mean = s * (1.f / 128.f);
        float inv  = rsqrtf(q * (1.f / 128.f) - mean * mean + EPS);
        int row = r0 + ri;
        float2 o;
        o.x = (h0 - mean) * s0v * inv + o0v;
        o.y = (h1 - mean) * s1v * inv + o1v;
        *(float2*)&out[(size_t)row * 256 + 128 + cidx] = o;
    }
}

extern "C" void kernel_launch(void* const* d_in, const int* in_sizes, int n_in,
                              void* d_out, int out_size, void* d_ws, size_t ws_size,
                              hipStream_t stream)
{
    const float* feat = (const float*)d_in[0];
    const float* W0   = (const float*)d_in[1];
    const float* b0   = (const float*)d_in[2];
    const float* s0   = (const float*)d_in[3];
    const float* o0   = (const float*)d_in[4];
    const float* W1   = (const float*)d_in[5];
    const float* b1   = (const float*)d_in[6];
    const float* s1   = (const float*)d_in[7];
    const float* o1   = (const float*)d_in[8];
    const int*   er   = (const int*)d_in[9];
    const int*   ec   = (const int*)d_in[10];
    const float* ev   = (const float*)d_in[11];
    float* out = (float*)d_out;

    // workspace layout (16B-aligned offsets), total ~21.4 MB
    char*   wsb   = (char*)d_ws;
    ushort* Wb    = (ushort*)(wsb);                 //    131,072 B
    ushort* Y1    = (ushort*)(wsb + 131072);        // 12,800,000 B
    int*    gcnt  = (int*)   (wsb + 12931072);      //     50,048 B (line-padded)
    uint2*  bedge = (uint2*) (wsb + 12981248);      //  8,408,064 B

    prep_small<<<1 + WB_BLOCKS, 256, 0, stream>>>(W0, W1, Wb, gcnt);

    gemm_scatter<<<SCATTER_BLOCKS + 2 * GEMM_MBLKS, 512, 0, stream>>>(
        feat, Wb, b0, s0, o0, out, Y1, er, ec, ev, gcnt, bedge);

    spmm_csr_ln<<<NBUCK, 512, 0, stream>>>(
        gcnt, bedge, Y1, b1, s1, o1, out);
}